// Round 2
// baseline (1136.012 us; speedup 1.0000x reference)
//
#include <hip/hip_runtime.h>
#include <stdint.h>
#include <math.h>

// ---------------- constants ----------------
#define SCALE  0.125f

typedef __bf16 bf16;
typedef __bf16 bf16x8 __attribute__((ext_vector_type(8)));
typedef float  f32x4  __attribute__((ext_vector_type(4)));

__device__ __forceinline__ ushort f2b(float f) {
  union { float f; uint32_t u; } v; v.f = f;
  uint32_t u = v.u;
  return (ushort)((u + 0x7fffu + ((u >> 16) & 1u)) >> 16);
}
__device__ __forceinline__ float b2f(ushort s) {
  union { uint32_t u; float f; } v; v.u = ((uint32_t)s) << 16;
  return v.f;
}
__device__ __forceinline__ void g2l16(const ushort* g, ushort* l) {
  __builtin_amdgcn_global_load_lds(
      (const __attribute__((address_space(1))) void*)g,
      (__attribute__((address_space(3))) void*)l, 16, 0, 0);
}

// ---------------- conversion kernels ----------------
// x: (S,B,N,D) f32 -> xb: (S,N,B,D) bf16
__global__ __launch_bounds__(256) void conv_x_kernel(const float* __restrict__ x,
                                                     ushort* __restrict__ xb) {
  int idx = blockIdx.x * 256 + threadIdx.x;
  int d4 = idx & 255;
  int n  = (idx >> 8) & 31;
  int b  = (idx >> 13) & 127;
  int s  = idx >> 20;
  float4 v = *(const float4*)(x + (size_t)(((s*128 + b)*32 + n) << 10) + (d4 << 2));
  ushort4 o;
  o.x = f2b(v.x); o.y = f2b(v.y); o.z = f2b(v.z); o.w = f2b(v.w);
  *(ushort4*)(xb + (size_t)(((s*32 + n)*128 + b) << 10) + (d4 << 2)) = o;
}

__global__ __launch_bounds__(256) void conv_q_kernel(const float* __restrict__ q,
                                                     ushort* __restrict__ qb) {
  int idx = blockIdx.x * 256 + threadIdx.x;
  float4 v = *(const float4*)(q + (size_t)idx * 4);
  ushort4 o;
  o.x = f2b(v.x); o.y = f2b(v.y); o.z = f2b(v.z); o.w = f2b(v.w);
  *(ushort4*)(qb + (size_t)idx * 4) = o;
}

// Wt[r][k] = W[k][srccol(r)] (bf16).
// mode 1 = W1 GLU interleave: per 32-row group g5: rows 0..15 -> a cols g5*16+w,
// rows 16..31 -> g cols 4096 + g5*16 + (w-16).  (a,g for hidden col h are 16 apart.)
__global__ __launch_bounds__(256) void transpose_w_kernel(const float* __restrict__ W,
                                                          ushort* __restrict__ Wt,
                                                          int K, int N, int mode) {
  __shared__ float tile[32][33];
  int rt = blockIdx.x, kt = blockIdx.y;
  int r0 = rt * 32;
  int tx = threadIdx.x & 31, ty = threadIdx.x >> 5;
  int src;
  if (mode == 1) {
    int rp = r0 + tx;
    int g5 = rp >> 5, w = rp & 31;
    src = (w < 16) ? (g5*16 + w) : (4096 + g5*16 + (w - 16));
  } else {
    src = r0 + tx;
  }
  for (int i = ty; i < 32; i += 8)
    tile[i][tx] = W[(size_t)(kt*32 + i) * N + src];
  __syncthreads();
  for (int i = ty; i < 32; i += 8)
    Wt[(size_t)(r0 + i) * K + kt*32 + tx] = f2b(tile[tx][i]);
}

// ---------------- main GEMM (bf16 A [MxK], bf16 Bt [NxK]) ----------------
// LDS layout is XOR-swizzled: logical col-group c (of 4 x 16B per 64B row)
// lives at physical slot c ^ ((row>>1)&3). Staging thread t therefore loads
// global group (t&3)^((t>>3)&3); fragment reads at (row,qq) read slot
// qq^((r>>1)&3). Result: ds_read_b128 is at most 2-way bank-aliased (free).
// EPI 0: store bf16 -> outb (stride Ncols)
// EPI 1: in-register GLU (interleaved W1t): j even = a, j odd = g ->
//        hidden bf16 (stride 4096); bias = b1 (8192)
// EPI 2: float out = acc + bias[col] + resid (stride Ncols)
template <int EPI>
__global__ __launch_bounds__(256) void gemm_bt(const ushort* __restrict__ A,
                                               const ushort* __restrict__ Bt,
                                               int K, int Ncols,
                                               float* __restrict__ outf,
                                               ushort* __restrict__ outb,
                                               const float* __restrict__ bias,
                                               const float* __restrict__ resid) {
  extern __shared__ char smem[];
  ushort* As = (ushort*)smem;          // 128x32 (swizzled)
  ushort* Bs = As + 4096;              // 128x32 (swizzled)
  const int nBn  = Ncols >> 7;
  const int bm = blockIdx.x / nBn, bn = blockIdx.x % nBn;
  const int t = threadIdx.x;
  const int wave = t >> 6, lane = t & 63;
  const int qq = lane >> 4, r = lane & 15;
  const int wm = ((wave >> 1) << 6), wn = ((wave & 1) << 6);
  const int swadj = (r >> 1) & 3;               // read-side swizzle
  const int aoff = ((qq ^ swadj) << 3);

  const int rstg = t >> 2;
  const int cstg = ((t & 3) ^ ((t >> 3) & 3)) << 3;   // write-side swizzle
  const ushort* ag0 = A  + (size_t)(bm*128 + rstg) * K + cstg;
  const ushort* ag1 = ag0 + (size_t)64 * K;
  const ushort* bg0 = Bt + (size_t)(bn*128 + rstg) * K + cstg;
  const ushort* bg1 = bg0 + (size_t)64 * K;
  ushort* asw0 = As + wave * 512;
  ushort* asw1 = As + 2048 + wave * 512;
  ushort* bsw0 = Bs + wave * 512;
  ushort* bsw1 = Bs + 2048 + wave * 512;

  f32x4 acc[4][4] = {};

  for (int k0 = 0; k0 < K; k0 += 32) {
    g2l16(ag0 + k0, asw0);
    g2l16(ag1 + k0, asw1);
    g2l16(bg0 + k0, bsw0);
    g2l16(bg1 + k0, bsw1);
    __syncthreads();
    bf16x8 af[4], bfr[4];
#pragma unroll
    for (int i = 0; i < 4; i++) af[i]  = *(const bf16x8*)(As + (wm + i*16 + r)*32 + aoff);
#pragma unroll
    for (int j = 0; j < 4; j++) bfr[j] = *(const bf16x8*)(Bs + (wn + j*16 + r)*32 + aoff);
#pragma unroll
    for (int i = 0; i < 4; i++)
#pragma unroll
      for (int j = 0; j < 4; j++)
        acc[i][j] = __builtin_amdgcn_mfma_f32_16x16x32_bf16(af[i], bfr[j], acc[i][j], 0, 0, 0);
    __syncthreads();
  }

  if (EPI == 0) {
#pragma unroll
    for (int i = 0; i < 4; i++)
#pragma unroll
      for (int j = 0; j < 4; j++)
#pragma unroll
        for (int ii = 0; ii < 4; ii++) {
          int row = bm*128 + wm + i*16 + qq*4 + ii;
          int col = bn*128 + wn + j*16 + r;
          outb[(size_t)row * Ncols + col] = f2b(acc[i][j][ii]);
        }
  } else if (EPI == 1) {
    // in-register GLU: physical tile col p = wn + j*16 + r;
    // (p&31)<16 -> a, else g; hidden col = bn*64 + (p>>5)*16 + r
#pragma unroll
    for (int jp = 0; jp < 2; jp++) {
      int j = jp * 2;
      int hcol = bn*64 + ((wave & 1)*2 + jp)*16 + r;
      float ba = bias[hcol];
      float bg = bias[4096 + hcol];
#pragma unroll
      for (int i = 0; i < 4; i++)
#pragma unroll
        for (int ii = 0; ii < 4; ii++) {
          float a = acc[i][j][ii]   + ba;
          float g = acc[i][j+1][ii] + bg;
          float ge = 0.5f * g * (1.0f + erff(g * 0.70710678118654752f));
          int row = bm*128 + wm + i*16 + qq*4 + ii;
          outb[(size_t)row * 4096 + hcol] = f2b(a * ge);
        }
    }
  } else {
#pragma unroll
    for (int i = 0; i < 4; i++)
#pragma unroll
      for (int j = 0; j < 4; j++)
#pragma unroll
        for (int ii = 0; ii < 4; ii++) {
          int row = bm*128 + wm + i*16 + qq*4 + ii;
          int col = bn*128 + wn + j*16 + r;
          size_t o = (size_t)row * Ncols + col;
          outf[o] = acc[i][j][ii] + bias[col] + resid[o];
        }
  }
}

// ---------------- attention ----------------
__global__ __launch_bounds__(256) void attn_kernel(const ushort* __restrict__ kv,
                                                   const ushort* __restrict__ qb,
                                                   const int* __restrict__ mask,
                                                   float* __restrict__ out) {
  __shared__ ushort Ks[128 * 72];
  __shared__ ushort Vt[64 * 136];
  __shared__ ushort Ps[64 * 136];
  __shared__ float  Mrow[128];

  const int bid = blockIdx.x;
  const int h = bid & 15, n = (bid >> 4) & 31, s = bid >> 9;
  const size_t kvbase = (size_t)((s*32 + n) * 128) * 2048;
  const int t = threadIdx.x, wave = t >> 6, lane = t & 63;
  const int qq = lane >> 4, r = lane & 15;

  if (t < 128) Mrow[t] = (mask[s*128 + t] == 0) ? 1.0f : 0.0f;

  for (int c = t; c < 1024; c += 256) {
    int b = c >> 3, d0 = (c & 7) * 8;
    uint4 v = *(const uint4*)(kv + kvbase + (size_t)b * 2048 + h*64 + d0);
    *(uint4*)(Ks + b*72 + d0) = v;
  }
  {
    int b = t & 127, dh = t >> 7;
    for (int jj = 0; jj < 32; jj += 8) {
      uint4 v = *(const uint4*)(kv + kvbase + (size_t)b * 2048 + 1024 + h*64 + dh*32 + jj);
      const ushort* pv = (const ushort*)&v;
#pragma unroll
      for (int u8 = 0; u8 < 8; u8++)
        Vt[(dh*32 + jj + u8)*136 + b] = pv[u8];
    }
  }
  __syncthreads();

  bf16x8 aq[2];
#pragma unroll
  for (int st = 0; st < 2; st++)
    aq[st] = *(const bf16x8*)(qb + (size_t)(wave*16 + r) * 1024 + h*64 + st*32 + qq*8);
  f32x4 sim[8];
#pragma unroll
  for (int jt = 0; jt < 8; jt++) {
    f32x4 c = {};
#pragma unroll
    for (int st = 0; st < 2; st++) {
      bf16x8 bk = *(const bf16x8*)(Ks + (jt*16 + r)*72 + st*32 + qq*8);
      c = __builtin_amdgcn_mfma_f32_16x16x32_bf16(aq[st], bk, c, 0, 0, 0);
    }
    sim[jt] = c;
  }

#pragma unroll
  for (int jt = 0; jt < 8; jt++) {
    float mflag = Mrow[jt*16 + r];
#pragma unroll
    for (int ii = 0; ii < 4; ii++) {
      float v = sim[jt][ii] * SCALE;
      sim[jt][ii] = (mflag > 0.5f) ? -1e10f : v;
    }
  }
  float mx[4] = {-3.0e38f, -3.0e38f, -3.0e38f, -3.0e38f};
#pragma unroll
  for (int jt = 0; jt < 8; jt++)
#pragma unroll
    for (int ii = 0; ii < 4; ii++) mx[ii] = fmaxf(mx[ii], sim[jt][ii]);
#pragma unroll
  for (int m = 1; m < 16; m <<= 1)
#pragma unroll
    for (int ii = 0; ii < 4; ii++) mx[ii] = fmaxf(mx[ii], __shfl_xor(mx[ii], m));
  float sm[4] = {0.f, 0.f, 0.f, 0.f};
#pragma unroll
  for (int jt = 0; jt < 8; jt++)
#pragma unroll
    for (int ii = 0; ii < 4; ii++) {
      float e = expf(sim[jt][ii] - mx[ii]);
      sim[jt][ii] = e;
      sm[ii] += e;
    }
#pragma unroll
  for (int m = 1; m < 16; m <<= 1)
#pragma unroll
    for (int ii = 0; ii < 4; ii++) sm[ii] += __shfl_xor(sm[ii], m);
#pragma unroll
  for (int ii = 0; ii < 4; ii++) sm[ii] = 1.0f / sm[ii];
#pragma unroll
  for (int jt = 0; jt < 8; jt++)
#pragma unroll
    for (int ii = 0; ii < 4; ii++)
      Ps[(wave*16 + qq*4 + ii)*136 + jt*16 + r] = f2b(sim[jt][ii] * sm[ii]);
  __syncthreads();

  f32x4 o[4] = {};
#pragma unroll
  for (int kst = 0; kst < 4; kst++) {
    bf16x8 ap = *(const bf16x8*)(Ps + (wave*16 + r)*136 + kst*32 + qq*8);
#pragma unroll
    for (int jt2 = 0; jt2 < 4; jt2++) {
      bf16x8 bv = *(const bf16x8*)(Vt + (jt2*16 + r)*136 + kst*32 + qq*8);
      o[jt2] = __builtin_amdgcn_mfma_f32_16x16x32_bf16(ap, bv, o[jt2], 0, 0, 0);
    }
  }
  const size_t orow0 = (size_t)((s*32 + n) * 64);
#pragma unroll
  for (int jt2 = 0; jt2 < 4; jt2++)
#pragma unroll
    for (int ii = 0; ii < 4; ii++) {
      int qr = wave*16 + qq*4 + ii;
      int d  = jt2*16 + r;
      out[(orow0 + qr) * 1024 + h*64 + d] = o[jt2][ii];
    }
}

// ---------------- LayerNorm (in-place) + bf16 copy ----------------
__global__ __launch_bounds__(256) void ln_kernel(float* __restrict__ y,
                                                 ushort* __restrict__ yb,
                                                 const float* __restrict__ g,
                                                 const float* __restrict__ b) {
  __shared__ float r1[4], r2[4];
  const int row = blockIdx.x, t = threadIdx.x;
  const int wave = t >> 6, lane = t & 63;
  float* p = y + (size_t)row * 1024;
  float4 v = *(const float4*)(p + t*4);
  float s1 = v.x + v.y + v.z + v.w;
  float s2 = v.x*v.x + v.y*v.y + v.z*v.z + v.w*v.w;
#pragma unroll
  for (int m = 1; m < 64; m <<= 1) { s1 += __shfl_xor(s1, m); s2 += __shfl_xor(s2, m); }
  if (lane == 0) { r1[wave] = s1; r2[wave] = s2; }
  __syncthreads();
  s1 = r1[0] + r1[1] + r1[2] + r1[3];
  s2 = r2[0] + r2[1] + r2[2] + r2[3];
  float mu  = s1 * (1.0f/1024.0f);
  float var = s2 * (1.0f/1024.0f) - mu*mu;
  float inv = rsqrtf(var + 1e-5f);
  float4 gg = *(const float4*)(g + t*4);
  float4 bb = *(const float4*)(b + t*4);
  float4 o;
  o.x = (v.x - mu)*inv*gg.x + bb.x;
  o.y = (v.y - mu)*inv*gg.y + bb.y;
  o.z = (v.z - mu)*inv*gg.z + bb.z;
  o.w = (v.w - mu)*inv*gg.w + bb.w;
  *(float4*)(p + t*4) = o;
  ushort4 ob; ob.x = f2b(o.x); ob.y = f2b(o.y); ob.z = f2b(o.z); ob.w = f2b(o.w);
  *(ushort4*)(yb + (size_t)row * 1024 + t*4) = ob;
}

// ---------------- launcher ----------------
extern "C" void kernel_launch(void* const* d_in, const int* in_sizes, int n_in,
                              void* d_out, int out_size, void* d_ws, size_t ws_size,
                              hipStream_t stream) {
  const float* x    = (const float*)d_in[0];
  const int*   mask = (const int*)  d_in[1];
  const float* q    = (const float*)d_in[2];
  const float* Wkv  = (const float*)d_in[3];
  const float* lng  = (const float*)d_in[4];
  const float* lnb  = (const float*)d_in[5];
  const float* b1   = (const float*)d_in[7];
  const float* W1   = (const float*)d_in[6];
  const float* W2   = (const float*)d_in[8];
  const float* b2   = (const float*)d_in[9];
  float* out = (float*)d_out;
  char* ws = (char*)d_ws;

  ushort* xb   = (ushort*)(ws);               // 64 MiB; dead after G1
  float*  yf   = (float*) (ws);               // alias: attn out / y
  ushort* kvb  = (ushort*)(ws + 67108864);    // 128 MiB; dead after attn
  ushort* hid  = (ushort*)(ws + 67108864);    // alias: hidden bf16
  ushort* yb   = (ushort*)(ws + 201326592);   // 32 MiB
  ushort* wkvt = (ushort*)(ws + 234881024);   // 4 MiB
  ushort* w1t  = (ushort*)(ws + 239075328);   // 16 MiB (GLU-interleaved rows)
  ushort* w2t  = (ushort*)(ws + 255852544);   // 8 MiB
  ushort* qb   = (ushort*)(ws + 264241152);   // 128 KiB

  conv_x_kernel<<<32768, 256, 0, stream>>>(x, xb);
  conv_q_kernel<<<64, 256, 0, stream>>>(q, qb);
  transpose_w_kernel<<<dim3(64, 32),  256, 0, stream>>>(Wkv, wkvt, 1024, 2048, 0);
  transpose_w_kernel<<<dim3(256, 32), 256, 0, stream>>>(W1,  w1t,  1024, 8192, 1);
  transpose_w_kernel<<<dim3(32, 128), 256, 0, stream>>>(W2,  w2t,  4096, 1024, 0);

  gemm_bt<0><<<4096, 256, 16384, stream>>>(xb, wkvt, 1024, 2048, nullptr, kvb, nullptr, nullptr);
  attn_kernel<<<4096, 256, 0, stream>>>(kvb, qb, mask, yf);
  ln_kernel<<<16384, 256, 0, stream>>>(yf, yb, lng, lnb);
  gemm_bt<1><<<8192, 256, 16384, stream>>>(yb, w1t, 1024, 8192, nullptr, hid, b1, nullptr);
  gemm_bt<2><<<1024, 256, 16384, stream>>>(hid, w2t, 4096, 1024, out, nullptr, b2, yf);
}

// Round 3
// 1034.937 us; speedup vs baseline: 1.0977x; 1.0977x over previous
//
#include <hip/hip_runtime.h>
#include <stdint.h>
#include <math.h>

// ---------------- constants ----------------
#define SCALE  0.125f

typedef __bf16 bf16;
typedef __bf16 bf16x8 __attribute__((ext_vector_type(8)));
typedef float  f32x4  __attribute__((ext_vector_type(4)));
typedef float  f32x16 __attribute__((ext_vector_type(16)));

__device__ __forceinline__ ushort f2b(float f) {
  union { float f; uint32_t u; } v; v.f = f;
  uint32_t u = v.u;
  return (ushort)((u + 0x7fffu + ((u >> 16) & 1u)) >> 16);
}
__device__ __forceinline__ float b2f(ushort s) {
  union { uint32_t u; float f; } v; v.u = ((uint32_t)s) << 16;
  return v.f;
}
__device__ __forceinline__ void g2l16(const ushort* g, ushort* l) {
  __builtin_amdgcn_global_load_lds(
      (const __attribute__((address_space(1))) void*)g,
      (__attribute__((address_space(3))) void*)l, 16, 0, 0);
}
// A&S 7.1.26 erf, |eps| <= 1.5e-7 (far below bf16 rounding). v_rcp + v_exp.
__device__ __forceinline__ float erf_fast(float x) {
  float ax = fabsf(x);
  float t  = __builtin_amdgcn_rcpf(1.0f + 0.3275911f * ax);
  float p  = t * (0.254829592f + t * (-0.284496736f + t * (1.421413741f +
             t * (-1.453152027f + t * 1.061405429f))));
  float e  = __expf(-ax * ax);
  float r  = 1.0f - p * e;
  return copysignf(r, x);
}

// ---------------- conversion kernels ----------------
// x: (S,B,N,D) f32 -> xb: (S,N,B,D) bf16
__global__ __launch_bounds__(256) void conv_x_kernel(const float* __restrict__ x,
                                                     ushort* __restrict__ xb) {
  int idx = blockIdx.x * 256 + threadIdx.x;
  int d4 = idx & 255;
  int n  = (idx >> 8) & 31;
  int b  = (idx >> 13) & 127;
  int s  = idx >> 20;
  float4 v = *(const float4*)(x + (size_t)(((s*128 + b)*32 + n) << 10) + (d4 << 2));
  ushort4 o;
  o.x = f2b(v.x); o.y = f2b(v.y); o.z = f2b(v.z); o.w = f2b(v.w);
  *(ushort4*)(xb + (size_t)(((s*32 + n)*128 + b) << 10) + (d4 << 2)) = o;
}

__global__ __launch_bounds__(256) void conv_q_kernel(const float* __restrict__ q,
                                                     ushort* __restrict__ qb) {
  int idx = blockIdx.x * 256 + threadIdx.x;
  float4 v = *(const float4*)(q + (size_t)idx * 4);
  ushort4 o;
  o.x = f2b(v.x); o.y = f2b(v.y); o.z = f2b(v.z); o.w = f2b(v.w);
  *(ushort4*)(qb + (size_t)idx * 4) = o;
}

// Wt[r][k] = W[k][srccol(r)] (bf16).
// mode 1 = W1 GLU interleave on 64-row groups: group g6 = r>>6, w = r&63:
//   w<32 -> a col g6*32+w ; w>=32 -> gate col 4096 + g6*32 + (w-32).
// With 32x32 MFMA tiles (wave n-quadrant = 64 cols) a and its gate partner
// land in the SAME lane: j=0 tile -> a, j=1 tile -> g, hidden col
// = bn*64 + (wave&1)*32 + (lane&31).
__global__ __launch_bounds__(256) void transpose_w_kernel(const float* __restrict__ W,
                                                          ushort* __restrict__ Wt,
                                                          int K, int N, int mode) {
  __shared__ float tile[32][33];
  int rt = blockIdx.x, kt = blockIdx.y;
  int r0 = rt * 32;
  int tx = threadIdx.x & 31, ty = threadIdx.x >> 5;
  int src;
  if (mode == 1) {
    int rp = r0 + tx;
    int g6 = rp >> 6, w = rp & 63;
    src = (w < 32) ? (g6*32 + w) : (4096 + g6*32 + (w - 32));
  } else {
    src = r0 + tx;
  }
  for (int i = ty; i < 32; i += 8)
    tile[i][tx] = W[(size_t)(kt*32 + i) * N + src];
  __syncthreads();
  for (int i = ty; i < 32; i += 8)
    Wt[(size_t)(r0 + i) * K + kt*32 + tx] = f2b(tile[tx][i]);
}

// ---------------- main GEMM (bf16 A [MxK], bf16 Bt [NxK]) ----------------
// 32x32x16 MFMA; 128x128 tile; 2x2 waves each owning a 64x64 quadrant of
// 2x2 32x32 acc tiles. LDS XOR-swizzled (store granule (t&3)^((t>>3)&3));
// fragment reads at (row, logical granule g) read slot g ^ ((row>>1)&3).
// K, NCOLS compile-time: staging offsets fold into load immediates; no
// per-iter address VALU. __launch_bounds__(256,4) caps unified regs at 128
// (acc 64 AGPR + frags 32 VGPR + addr) -> 4 blocks/CU to cover barrier drains.
// EPI 0: store bf16 -> outb (stride NCOLS)
// EPI 1: in-register GLU (64-group-interleaved W1t) -> hidden bf16 (stride 4096)
// EPI 2: float out = acc + bias[col] + resid (stride NCOLS)
template <int EPI, int K, int NCOLS>
__global__ __launch_bounds__(256, 4) void gemm_bt(const ushort* __restrict__ A,
                                                  const ushort* __restrict__ Bt,
                                                  float* __restrict__ outf,
                                                  ushort* __restrict__ outb,
                                                  const float* __restrict__ bias,
                                                  const float* __restrict__ resid) {
  __shared__ ushort As[128 * 32];
  __shared__ ushort Bs[128 * 32];
  constexpr int nBn = NCOLS >> 7;
  const int bm = blockIdx.x / nBn, bn = blockIdx.x % nBn;
  const int t = threadIdx.x;
  const int wave = t >> 6, lane = t & 63;
  const int c32 = lane & 31, hi = lane >> 5;
  const int wm = ((wave >> 1) << 6), wn = ((wave & 1) << 6);
  const int swz = (c32 >> 1) & 3;   // read-side swizzle for this lane's row

  const int rstg = t >> 2;
  const int cstg = ((t & 3) ^ ((t >> 3) & 3)) << 3;   // write-side swizzle
  const ushort* ag0 = A  + (size_t)(bm*128 + rstg) * K + cstg;
  const ushort* ag1 = ag0 + (size_t)64 * K;
  const ushort* bg0 = Bt + (size_t)(bn*128 + rstg) * K + cstg;
  const ushort* bg1 = bg0 + (size_t)64 * K;
  ushort* asw0 = As + wave * 512;
  ushort* asw1 = As + 2048 + wave * 512;
  ushort* bsw0 = Bs + wave * 512;
  ushort* bsw1 = Bs + 2048 + wave * 512;

  f32x16 acc[2][2] = {};

#pragma unroll 8
  for (int k0 = 0; k0 < K; k0 += 32) {
    g2l16(ag0 + k0, asw0);
    g2l16(ag1 + k0, asw1);
    g2l16(bg0 + k0, bsw0);
    g2l16(bg1 + k0, bsw1);
    __syncthreads();
    bf16x8 af[2][2], bfr[2][2];   // [tile][kstep]
#pragma unroll
    for (int i = 0; i < 2; i++)
#pragma unroll
      for (int ks = 0; ks < 2; ks++) {
        int row = wm + i*32 + c32;
        int pg  = ((ks*2 + hi) ^ swz) << 3;
        af[i][ks] = *(const bf16x8*)(As + row*32 + pg);
      }
#pragma unroll
    for (int j = 0; j < 2; j++)
#pragma unroll
      for (int ks = 0; ks < 2; ks++) {
        int row = wn + j*32 + c32;
        int pg  = ((ks*2 + hi) ^ swz) << 3;
        bfr[j][ks] = *(const bf16x8*)(Bs + row*32 + pg);
      }
#pragma unroll
    for (int ks = 0; ks < 2; ks++)
#pragma unroll
      for (int i = 0; i < 2; i++)
#pragma unroll
        for (int j = 0; j < 2; j++)
          acc[i][j] = __builtin_amdgcn_mfma_f32_32x32x16_bf16(af[i][ks], bfr[j][ks], acc[i][j], 0, 0, 0);
    __syncthreads();
  }

  // C/D layout (m74/m101): col = lane&31, row = (reg&3) + 8*(reg>>2) + 4*(lane>>5)
  if (EPI == 0) {
#pragma unroll
    for (int i = 0; i < 2; i++)
#pragma unroll
      for (int j = 0; j < 2; j++)
#pragma unroll
        for (int reg = 0; reg < 16; reg++) {
          int row = bm*128 + wm + i*32 + (reg & 3) + 8*(reg >> 2) + 4*hi;
          int col = bn*128 + wn + j*32 + c32;
          outb[(size_t)row * NCOLS + col] = f2b(acc[i][j][reg]);
        }
  } else if (EPI == 1) {
    int hcol = bn*64 + (wave & 1)*32 + c32;
    float ba = bias[hcol];
    float bg = bias[4096 + hcol];
#pragma unroll
    for (int i = 0; i < 2; i++)
#pragma unroll
      for (int reg = 0; reg < 16; reg++) {
        float a = acc[i][0][reg] + ba;
        float g = acc[i][1][reg] + bg;
        float ge = 0.5f * g * (1.0f + erf_fast(g * 0.70710678118654752f));
        int row = bm*128 + wm + i*32 + (reg & 3) + 8*(reg >> 2) + 4*hi;
        outb[(size_t)row * 4096 + hcol] = f2b(a * ge);
      }
  } else {
#pragma unroll
    for (int i = 0; i < 2; i++)
#pragma unroll
      for (int j = 0; j < 2; j++) {
        int col = bn*128 + wn + j*32 + c32;
        float bc = bias[col];
#pragma unroll
        for (int reg = 0; reg < 16; reg++) {
          int row = bm*128 + wm + i*32 + (reg & 3) + 8*(reg >> 2) + 4*hi;
          size_t o = (size_t)row * NCOLS + col;
          outf[o] = acc[i][j][reg] + bc + resid[o];
        }
      }
  }
}

// ---------------- attention ----------------
__global__ __launch_bounds__(256) void attn_kernel(const ushort* __restrict__ kv,
                                                   const ushort* __restrict__ qb,
                                                   const int* __restrict__ mask,
                                                   float* __restrict__ out) {
  __shared__ ushort Ks[128 * 72];
  __shared__ ushort Vt[64 * 136];
  __shared__ ushort Ps[64 * 136];
  __shared__ float  Mrow[128];

  const int bid = blockIdx.x;
  const int h = bid & 15, n = (bid >> 4) & 31, s = bid >> 9;
  const size_t kvbase = (size_t)((s*32 + n) * 128) * 2048;
  const int t = threadIdx.x, wave = t >> 6, lane = t & 63;
  const int qq = lane >> 4, r = lane & 15;

  if (t < 128) Mrow[t] = (mask[s*128 + t] == 0) ? 1.0f : 0.0f;

  for (int c = t; c < 1024; c += 256) {
    int b = c >> 3, d0 = (c & 7) * 8;
    uint4 v = *(const uint4*)(kv + kvbase + (size_t)b * 2048 + h*64 + d0);
    *(uint4*)(Ks + b*72 + d0) = v;
  }
  {
    int b = t & 127, dh = t >> 7;
    for (int jj = 0; jj < 32; jj += 8) {
      uint4 v = *(const uint4*)(kv + kvbase + (size_t)b * 2048 + 1024 + h*64 + dh*32 + jj);
      const ushort* pv = (const ushort*)&v;
#pragma unroll
      for (int u8 = 0; u8 < 8; u8++)
        Vt[(dh*32 + jj + u8)*136 + b] = pv[u8];
    }
  }
  __syncthreads();

  bf16x8 aq[2];
#pragma unroll
  for (int st = 0; st < 2; st++)
    aq[st] = *(const bf16x8*)(qb + (size_t)(wave*16 + r) * 1024 + h*64 + st*32 + qq*8);
  f32x4 sim[8];
#pragma unroll
  for (int jt = 0; jt < 8; jt++) {
    f32x4 c = {};
#pragma unroll
    for (int st = 0; st < 2; st++) {
      bf16x8 bk = *(const bf16x8*)(Ks + (jt*16 + r)*72 + st*32 + qq*8);
      c = __builtin_amdgcn_mfma_f32_16x16x32_bf16(aq[st], bk, c, 0, 0, 0);
    }
    sim[jt] = c;
  }

#pragma unroll
  for (int jt = 0; jt < 8; jt++) {
    float mflag = Mrow[jt*16 + r];
#pragma unroll
    for (int ii = 0; ii < 4; ii++) {
      float v = sim[jt][ii] * SCALE;
      sim[jt][ii] = (mflag > 0.5f) ? -1e10f : v;
    }
  }
  float mx[4] = {-3.0e38f, -3.0e38f, -3.0e38f, -3.0e38f};
#pragma unroll
  for (int jt = 0; jt < 8; jt++)
#pragma unroll
    for (int ii = 0; ii < 4; ii++) mx[ii] = fmaxf(mx[ii], sim[jt][ii]);
#pragma unroll
  for (int m = 1; m < 16; m <<= 1)
#pragma unroll
    for (int ii = 0; ii < 4; ii++) mx[ii] = fmaxf(mx[ii], __shfl_xor(mx[ii], m));
  float sm[4] = {0.f, 0.f, 0.f, 0.f};
#pragma unroll
  for (int jt = 0; jt < 8; jt++)
#pragma unroll
    for (int ii = 0; ii < 4; ii++) {
      float e = expf(sim[jt][ii] - mx[ii]);
      sim[jt][ii] = e;
      sm[ii] += e;
    }
#pragma unroll
  for (int m = 1; m < 16; m <<= 1)
#pragma unroll
    for (int ii = 0; ii < 4; ii++) sm[ii] += __shfl_xor(sm[ii], m);
#pragma unroll
  for (int ii = 0; ii < 4; ii++) sm[ii] = 1.0f / sm[ii];
#pragma unroll
  for (int jt = 0; jt < 8; jt++)
#pragma unroll
    for (int ii = 0; ii < 4; ii++)
      Ps[(wave*16 + qq*4 + ii)*136 + jt*16 + r] = f2b(sim[jt][ii] * sm[ii]);
  __syncthreads();

  f32x4 o[4] = {};
#pragma unroll
  for (int kst = 0; kst < 4; kst++) {
    bf16x8 ap = *(const bf16x8*)(Ps + (wave*16 + r)*136 + kst*32 + qq*8);
#pragma unroll
    for (int jt2 = 0; jt2 < 4; jt2++) {
      bf16x8 bv = *(const bf16x8*)(Vt + (jt2*16 + r)*136 + kst*32 + qq*8);
      o[jt2] = __builtin_amdgcn_mfma_f32_16x16x32_bf16(ap, bv, o[jt2], 0, 0, 0);
    }
  }
  const size_t orow0 = (size_t)((s*32 + n) * 64);
#pragma unroll
  for (int jt2 = 0; jt2 < 4; jt2++)
#pragma unroll
    for (int ii = 0; ii < 4; ii++) {
      int qr = wave*16 + qq*4 + ii;
      int d  = jt2*16 + r;
      out[(orow0 + qr) * 1024 + h*64 + d] = o[jt2][ii];
    }
}

// ---------------- LayerNorm (in-place) + bf16 copy ----------------
__global__ __launch_bounds__(256) void ln_kernel(float* __restrict__ y,
                                                 ushort* __restrict__ yb,
                                                 const float* __restrict__ g,
                                                 const float* __restrict__ b) {
  __shared__ float r1[4], r2[4];
  const int row = blockIdx.x, t = threadIdx.x;
  const int wave = t >> 6, lane = t & 63;
  float* p = y + (size_t)row * 1024;
  float4 v = *(const float4*)(p + t*4);
  float s1 = v.x + v.y + v.z + v.w;
  float s2 = v.x*v.x + v.y*v.y + v.z*v.z + v.w*v.w;
#pragma unroll
  for (int m = 1; m < 64; m <<= 1) { s1 += __shfl_xor(s1, m); s2 += __shfl_xor(s2, m); }
  if (lane == 0) { r1[wave] = s1; r2[wave] = s2; }
  __syncthreads();
  s1 = r1[0] + r1[1] + r1[2] + r1[3];
  s2 = r2[0] + r2[1] + r2[2] + r2[3];
  float mu  = s1 * (1.0f/1024.0f);
  float var = s2 * (1.0f/1024.0f) - mu*mu;
  float inv = rsqrtf(var + 1e-5f);
  float4 gg = *(const float4*)(g + t*4);
  float4 bb = *(const float4*)(b + t*4);
  float4 o;
  o.x = (v.x - mu)*inv*gg.x + bb.x;
  o.y = (v.y - mu)*inv*gg.y + bb.y;
  o.z = (v.z - mu)*inv*gg.z + bb.z;
  o.w = (v.w - mu)*inv*gg.w + bb.w;
  *(float4*)(p + t*4) = o;
  ushort4 ob; ob.x = f2b(o.x); ob.y = f2b(o.y); ob.z = f2b(o.z); ob.w = f2b(o.w);
  *(ushort4*)(yb + (size_t)row * 1024 + t*4) = ob;
}

// ---------------- launcher ----------------
extern "C" void kernel_launch(void* const* d_in, const int* in_sizes, int n_in,
                              void* d_out, int out_size, void* d_ws, size_t ws_size,
                              hipStream_t stream) {
  const float* x    = (const float*)d_in[0];
  const int*   mask = (const int*)  d_in[1];
  const float* q    = (const float*)d_in[2];
  const float* Wkv  = (const float*)d_in[3];
  const float* lng  = (const float*)d_in[4];
  const float* lnb  = (const float*)d_in[5];
  const float* W1   = (const float*)d_in[6];
  const float* b1   = (const float*)d_in[7];
  const float* W2   = (const float*)d_in[8];
  const float* b2   = (const float*)d_in[9];
  float* out = (float*)d_out;
  char* ws = (char*)d_ws;

  ushort* xb   = (ushort*)(ws);               // 64 MiB; dead after G1
  float*  yf   = (float*) (ws);               // alias: attn out / y
  ushort* kvb  = (ushort*)(ws + 67108864);    // 128 MiB; dead after attn
  ushort* hid  = (ushort*)(ws + 67108864);    // alias: hidden bf16
  ushort* yb   = (ushort*)(ws + 201326592);   // 32 MiB
  ushort* wkvt = (ushort*)(ws + 234881024);   // 4 MiB
  ushort* w1t  = (ushort*)(ws + 239075328);   // 16 MiB (GLU 64-group interleave)
  ushort* w2t  = (ushort*)(ws + 255852544);   // 8 MiB
  ushort* qb   = (ushort*)(ws + 264241152);   // 128 KiB

  conv_x_kernel<<<32768, 256, 0, stream>>>(x, xb);
  conv_q_kernel<<<64, 256, 0, stream>>>(q, qb);
  transpose_w_kernel<<<dim3(64, 32),  256, 0, stream>>>(Wkv, wkvt, 1024, 2048, 0);
  transpose_w_kernel<<<dim3(256, 32), 256, 0, stream>>>(W1,  w1t,  1024, 8192, 1);
  transpose_w_kernel<<<dim3(32, 128), 256, 0, stream>>>(W2,  w2t,  4096, 1024, 0);

  gemm_bt<0, 1024, 2048><<<4096, 256, 0, stream>>>(xb, wkvt, nullptr, kvb, nullptr, nullptr);
  attn_kernel<<<4096, 256, 0, stream>>>(kvb, qb, mask, yf);
  ln_kernel<<<16384, 256, 0, stream>>>(yf, yb, lng, lnb);
  gemm_bt<1, 1024, 8192><<<8192, 256, 0, stream>>>(yb, w1t, nullptr, hid, b1, nullptr);
  gemm_bt<2, 4096, 1024><<<1024, 256, 0, stream>>>(hid, w2t, out, nullptr, b2, yf);
}

// Round 4
// 946.624 us; speedup vs baseline: 1.2001x; 1.0933x over previous
//
#include <hip/hip_runtime.h>
#include <stdint.h>
#include <math.h>

// ---------------- constants ----------------
#define SCALE  0.125f

typedef __bf16 bf16;
typedef __bf16 bf16x8 __attribute__((ext_vector_type(8)));
typedef float  f32x4  __attribute__((ext_vector_type(4)));
typedef float  f32x16 __attribute__((ext_vector_type(16)));

__device__ __forceinline__ ushort f2b(float f) {
  union { float f; uint32_t u; } v; v.f = f;
  uint32_t u = v.u;
  return (ushort)((u + 0x7fffu + ((u >> 16) & 1u)) >> 16);
}
__device__ __forceinline__ float b2f(ushort s) {
  union { uint32_t u; float f; } v; v.u = ((uint32_t)s) << 16;
  return v.f;
}
__device__ __forceinline__ void g2l16(const ushort* g, ushort* l) {
  __builtin_amdgcn_global_load_lds(
      (const __attribute__((address_space(1))) void*)g,
      (__attribute__((address_space(3))) void*)l, 16, 0, 0);
}
// A&S 7.1.26 erf, |eps| <= 1.5e-7 (far below bf16 rounding). v_rcp + v_exp.
__device__ __forceinline__ float erf_fast(float x) {
  float ax = fabsf(x);
  float t  = __builtin_amdgcn_rcpf(1.0f + 0.3275911f * ax);
  float p  = t * (0.254829592f + t * (-0.284496736f + t * (1.421413741f +
             t * (-1.453152027f + t * 1.061405429f))));
  float e  = __expf(-ax * ax);
  float r  = 1.0f - p * e;
  return copysignf(r, x);
}

// ---------------- conversion kernels ----------------
// x: (S,B,N,D) f32 -> xb: (S,N,B,D) bf16
__global__ __launch_bounds__(256) void conv_x_kernel(const float* __restrict__ x,
                                                     ushort* __restrict__ xb) {
  int idx = blockIdx.x * 256 + threadIdx.x;
  int d4 = idx & 255;
  int n  = (idx >> 8) & 31;
  int b  = (idx >> 13) & 127;
  int s  = idx >> 20;
  float4 v = *(const float4*)(x + (size_t)(((s*128 + b)*32 + n) << 10) + (d4 << 2));
  ushort4 o;
  o.x = f2b(v.x); o.y = f2b(v.y); o.z = f2b(v.z); o.w = f2b(v.w);
  *(ushort4*)(xb + (size_t)(((s*32 + n)*128 + b) << 10) + (d4 << 2)) = o;
}

__global__ __launch_bounds__(256) void conv_q_kernel(const float* __restrict__ q,
                                                     ushort* __restrict__ qb) {
  int idx = blockIdx.x * 256 + threadIdx.x;
  float4 v = *(const float4*)(q + (size_t)idx * 4);
  ushort4 o;
  o.x = f2b(v.x); o.y = f2b(v.y); o.z = f2b(v.z); o.w = f2b(v.w);
  *(ushort4*)(qb + (size_t)idx * 4) = o;
}

// Wt[r][k] = W[k][srccol(r)] (bf16).
// mode 1 = W1 GLU interleave on 64-row groups: group g6 = r>>6, w = r&63:
//   w<32 -> a col g6*32+w ; w>=32 -> gate col 4096 + g6*32 + (w-32).
__global__ __launch_bounds__(256) void transpose_w_kernel(const float* __restrict__ W,
                                                          ushort* __restrict__ Wt,
                                                          int K, int N, int mode) {
  __shared__ float tile[32][33];
  int rt = blockIdx.x, kt = blockIdx.y;
  int r0 = rt * 32;
  int tx = threadIdx.x & 31, ty = threadIdx.x >> 5;
  int src;
  if (mode == 1) {
    int rp = r0 + tx;
    int g6 = rp >> 6, w = rp & 63;
    src = (w < 32) ? (g6*32 + w) : (4096 + g6*32 + (w - 32));
  } else {
    src = r0 + tx;
  }
  for (int i = ty; i < 32; i += 8)
    tile[i][tx] = W[(size_t)(kt*32 + i) * N + src];
  __syncthreads();
  for (int i = ty; i < 32; i += 8)
    Wt[(size_t)(r0 + i) * K + kt*32 + tx] = f2b(tile[tx][i]);
}

// ---------------- main GEMM (bf16 A [MxK], bf16 Bt [NxK]) ----------------
// 32x32x16 MFMA; 128x128 tile; BK=64 (16KB A + 16KB B LDS, 4 blocks/CU).
// LDS layout: tile row = 128B = 8 granules of 16B; granule kg of row r lives
// at slot kg ^ (r&7). Staging thread t fetches granule (t&7)^((t>>3)&7) of its
// row (still 128B-contiguous per row -> fully coalesced). Fragment read for
// (ks,hi) hits slot (2ks+hi)^(c32&7): any aligned 8-lane group covers all 8
// slot positions = all 32 banks -> conflict-free in lane order (round-2
// empirics). K, NCOLS compile-time. __launch_bounds__(256,4) -> 4 blocks/CU.
// EPI 0: store bf16 -> outb (stride NCOLS)
// EPI 1: in-register GLU (64-group-interleaved W1t) -> hidden bf16 (stride 4096)
// EPI 2: float out = acc + bias[col] + resid (stride NCOLS)
template <int EPI, int K, int NCOLS>
__global__ __launch_bounds__(256, 4) void gemm_bt(const ushort* __restrict__ A,
                                                  const ushort* __restrict__ Bt,
                                                  float* __restrict__ outf,
                                                  ushort* __restrict__ outb,
                                                  const float* __restrict__ bias,
                                                  const float* __restrict__ resid) {
  __shared__ ushort As[128 * 64];
  __shared__ ushort Bs[128 * 64];
  constexpr int nBn = NCOLS >> 7;
  const int bm = blockIdx.x / nBn, bn = blockIdx.x % nBn;
  const int t = threadIdx.x;
  const int wave = t >> 6, lane = t & 63;
  const int c32 = lane & 31, hi = lane >> 5;
  const int wm = ((wave >> 1) << 6), wn = ((wave & 1) << 6);
  const int swz = c32 & 7;

  // staging: call c covers rows [c*32 + wave*8, +8); lane l -> row +(l>>3),
  // slot l&7, source granule (l&7)^((l>>3)&7)
  const int srow = wave*8 + (lane >> 3);
  const int skg  = (lane & 7) ^ ((lane >> 3) & 7);
  const ushort* ag = A  + (size_t)(bm*128 + srow) * K + skg*8;
  const ushort* bg = Bt + (size_t)(bn*128 + srow) * K + skg*8;
  ushort* asl = As + wave * 512;
  ushort* bsl = Bs + wave * 512;

  f32x16 acc[2][2] = {};

#pragma unroll 2
  for (int k0 = 0; k0 < K; k0 += 64) {
#pragma unroll
    for (int c = 0; c < 4; c++) {
      g2l16(ag + (size_t)c*32*K + k0, asl + c*2048);
      g2l16(bg + (size_t)c*32*K + k0, bsl + c*2048);
    }
    __syncthreads();
#pragma unroll
    for (int kb = 0; kb < 2; kb++) {
      bf16x8 af[2][2], bfr[2][2];   // [tile][ks-within-batch]
#pragma unroll
      for (int i = 0; i < 2; i++)
#pragma unroll
        for (int k2 = 0; k2 < 2; k2++) {
          int ks = kb*2 + k2;
          int ps = (2*ks + hi) ^ swz;
          af[i][k2]  = *(const bf16x8*)(As + (wm + i*32 + c32)*64 + ps*8);
          bfr[i][k2] = *(const bf16x8*)(Bs + (wn + i*32 + c32)*64 + ps*8);
        }
#pragma unroll
      for (int k2 = 0; k2 < 2; k2++)
#pragma unroll
        for (int i = 0; i < 2; i++)
#pragma unroll
          for (int j = 0; j < 2; j++)
            acc[i][j] = __builtin_amdgcn_mfma_f32_32x32x16_bf16(af[i][k2], bfr[j][k2], acc[i][j], 0, 0, 0);
    }
    __syncthreads();
  }

  // C/D layout (m74/m101): col = lane&31, row = (reg&3) + 8*(reg>>2) + 4*(lane>>5)
  if (EPI == 0) {
#pragma unroll
    for (int i = 0; i < 2; i++)
#pragma unroll
      for (int j = 0; j < 2; j++)
#pragma unroll
        for (int reg = 0; reg < 16; reg++) {
          int row = bm*128 + wm + i*32 + (reg & 3) + 8*(reg >> 2) + 4*hi;
          int col = bn*128 + wn + j*32 + c32;
          outb[(size_t)row * NCOLS + col] = f2b(acc[i][j][reg]);
        }
  } else if (EPI == 1) {
    int hcol = bn*64 + (wave & 1)*32 + c32;
    float ba = bias[hcol];
    float bg2 = bias[4096 + hcol];
#pragma unroll
    for (int i = 0; i < 2; i++)
#pragma unroll
      for (int reg = 0; reg < 16; reg++) {
        float a = acc[i][0][reg] + ba;
        float g = acc[i][1][reg] + bg2;
        float ge = 0.5f * g * (1.0f + erf_fast(g * 0.70710678118654752f));
        int row = bm*128 + wm + i*32 + (reg & 3) + 8*(reg >> 2) + 4*hi;
        outb[(size_t)row * 4096 + hcol] = f2b(a * ge);
      }
  } else {
#pragma unroll
    for (int i = 0; i < 2; i++)
#pragma unroll
      for (int j = 0; j < 2; j++) {
        int col = bn*128 + wn + j*32 + c32;
        float bc = bias[col];
#pragma unroll
        for (int reg = 0; reg < 16; reg++) {
          int row = bm*128 + wm + i*32 + (reg & 3) + 8*(reg >> 2) + 4*hi;
          size_t o = (size_t)row * NCOLS + col;
          outf[o] = acc[i][j][reg] + bc + resid[o];
        }
      }
  }
}

// ---------------- attention ----------------
__global__ __launch_bounds__(256) void attn_kernel(const ushort* __restrict__ kv,
                                                   const ushort* __restrict__ qb,
                                                   const int* __restrict__ mask,
                                                   float* __restrict__ out) {
  __shared__ ushort Ks[128 * 72];
  __shared__ ushort Vt[64 * 136];
  __shared__ ushort Ps[64 * 136];
  __shared__ float  Mrow[128];

  const int bid = blockIdx.x;
  const int h = bid & 15, n = (bid >> 4) & 31, s = bid >> 9;
  const size_t kvbase = (size_t)((s*32 + n) * 128) * 2048;
  const int t = threadIdx.x, wave = t >> 6, lane = t & 63;
  const int qq = lane >> 4, r = lane & 15;

  if (t < 128) Mrow[t] = (mask[s*128 + t] == 0) ? 1.0f : 0.0f;

  for (int c = t; c < 1024; c += 256) {
    int b = c >> 3, d0 = (c & 7) * 8;
    uint4 v = *(const uint4*)(kv + kvbase + (size_t)b * 2048 + h*64 + d0);
    *(uint4*)(Ks + b*72 + d0) = v;
  }
  {
    int b = t & 127, dh = t >> 7;
    for (int jj = 0; jj < 32; jj += 8) {
      uint4 v = *(const uint4*)(kv + kvbase + (size_t)b * 2048 + 1024 + h*64 + dh*32 + jj);
      const ushort* pv = (const ushort*)&v;
#pragma unroll
      for (int u8 = 0; u8 < 8; u8++)
        Vt[(dh*32 + jj + u8)*136 + b] = pv[u8];
    }
  }
  __syncthreads();

  bf16x8 aq[2];
#pragma unroll
  for (int st = 0; st < 2; st++)
    aq[st] = *(const bf16x8*)(qb + (size_t)(wave*16 + r) * 1024 + h*64 + st*32 + qq*8);
  f32x4 sim[8];
#pragma unroll
  for (int jt = 0; jt < 8; jt++) {
    f32x4 c = {};
#pragma unroll
    for (int st = 0; st < 2; st++) {
      bf16x8 bk = *(const bf16x8*)(Ks + (jt*16 + r)*72 + st*32 + qq*8);
      c = __builtin_amdgcn_mfma_f32_16x16x32_bf16(aq[st], bk, c, 0, 0, 0);
    }
    sim[jt] = c;
  }

#pragma unroll
  for (int jt = 0; jt < 8; jt++) {
    float mflag = Mrow[jt*16 + r];
#pragma unroll
    for (int ii = 0; ii < 4; ii++) {
      float v = sim[jt][ii] * SCALE;
      sim[jt][ii] = (mflag > 0.5f) ? -1e10f : v;
    }
  }
  float mx[4] = {-3.0e38f, -3.0e38f, -3.0e38f, -3.0e38f};
#pragma unroll
  for (int jt = 0; jt < 8; jt++)
#pragma unroll
    for (int ii = 0; ii < 4; ii++) mx[ii] = fmaxf(mx[ii], sim[jt][ii]);
#pragma unroll
  for (int m = 1; m < 16; m <<= 1)
#pragma unroll
    for (int ii = 0; ii < 4; ii++) mx[ii] = fmaxf(mx[ii], __shfl_xor(mx[ii], m));
  float sm[4] = {0.f, 0.f, 0.f, 0.f};
#pragma unroll
  for (int jt = 0; jt < 8; jt++)
#pragma unroll
    for (int ii = 0; ii < 4; ii++) {
      float e = expf(sim[jt][ii] - mx[ii]);
      sim[jt][ii] = e;
      sm[ii] += e;
    }
#pragma unroll
  for (int m = 1; m < 16; m <<= 1)
#pragma unroll
    for (int ii = 0; ii < 4; ii++) sm[ii] += __shfl_xor(sm[ii], m);
#pragma unroll
  for (int ii = 0; ii < 4; ii++) sm[ii] = 1.0f / sm[ii];
#pragma unroll
  for (int jt = 0; jt < 8; jt++)
#pragma unroll
    for (int ii = 0; ii < 4; ii++)
      Ps[(wave*16 + qq*4 + ii)*136 + jt*16 + r] = f2b(sim[jt][ii] * sm[ii]);
  __syncthreads();

  f32x4 o[4] = {};
#pragma unroll
  for (int kst = 0; kst < 4; kst++) {
    bf16x8 ap = *(const bf16x8*)(Ps + (wave*16 + r)*136 + kst*32 + qq*8);
#pragma unroll
    for (int jt2 = 0; jt2 < 4; jt2++) {
      bf16x8 bv = *(const bf16x8*)(Vt + (jt2*16 + r)*136 + kst*32 + qq*8);
      o[jt2] = __builtin_amdgcn_mfma_f32_16x16x32_bf16(ap, bv, o[jt2], 0, 0, 0);
    }
  }
  const size_t orow0 = (size_t)((s*32 + n) * 64);
#pragma unroll
  for (int jt2 = 0; jt2 < 4; jt2++)
#pragma unroll
    for (int ii = 0; ii < 4; ii++) {
      int qr = wave*16 + qq*4 + ii;
      int d  = jt2*16 + r;
      out[(orow0 + qr) * 1024 + h*64 + d] = o[jt2][ii];
    }
}

// ---------------- LayerNorm (in-place) + bf16 copy ----------------
__global__ __launch_bounds__(256) void ln_kernel(float* __restrict__ y,
                                                 ushort* __restrict__ yb,
                                                 const float* __restrict__ g,
                                                 const float* __restrict__ b) {
  __shared__ float r1[4], r2[4];
  const int row = blockIdx.x, t = threadIdx.x;
  const int wave = t >> 6, lane = t & 63;
  float* p = y + (size_t)row * 1024;
  float4 v = *(const float4*)(p + t*4);
  float s1 = v.x + v.y + v.z + v.w;
  float s2 = v.x*v.x + v.y*v.y + v.z*v.z + v.w*v.w;
#pragma unroll
  for (int m = 1; m < 64; m <<= 1) { s1 += __shfl_xor(s1, m); s2 += __shfl_xor(s2, m); }
  if (lane == 0) { r1[wave] = s1; r2[wave] = s2; }
  __syncthreads();
  s1 = r1[0] + r1[1] + r1[2] + r1[3];
  s2 = r2[0] + r2[1] + r2[2] + r2[3];
  float mu  = s1 * (1.0f/1024.0f);
  float var = s2 * (1.0f/1024.0f) - mu*mu;
  float inv = rsqrtf(var + 1e-5f);
  float4 gg = *(const float4*)(g + t*4);
  float4 bb = *(const float4*)(b + t*4);
  float4 o;
  o.x = (v.x - mu)*inv*gg.x + bb.x;
  o.y = (v.y - mu)*inv*gg.y + bb.y;
  o.z = (v.z - mu)*inv*gg.z + bb.z;
  o.w = (v.w - mu)*inv*gg.w + bb.w;
  *(float4*)(p + t*4) = o;
  ushort4 ob; ob.x = f2b(o.x); ob.y = f2b(o.y); ob.z = f2b(o.z); ob.w = f2b(o.w);
  *(ushort4*)(yb + (size_t)row * 1024 + t*4) = ob;
}

// ---------------- launcher ----------------
extern "C" void kernel_launch(void* const* d_in, const int* in_sizes, int n_in,
                              void* d_out, int out_size, void* d_ws, size_t ws_size,
                              hipStream_t stream) {
  const float* x    = (const float*)d_in[0];
  const int*   mask = (const int*)  d_in[1];
  const float* q    = (const float*)d_in[2];
  const float* Wkv  = (const float*)d_in[3];
  const float* lng  = (const float*)d_in[4];
  const float* lnb  = (const float*)d_in[5];
  const float* W1   = (const float*)d_in[6];
  const float* b1   = (const float*)d_in[7];
  const float* W2   = (const float*)d_in[8];
  const float* b2   = (const float*)d_in[9];
  float* out = (float*)d_out;
  char* ws = (char*)d_ws;

  ushort* xb   = (ushort*)(ws);               // 64 MiB; dead after G1
  float*  yf   = (float*) (ws);               // alias: attn out / y
  ushort* kvb  = (ushort*)(ws + 67108864);    // 128 MiB; dead after attn
  ushort* hid  = (ushort*)(ws + 67108864);    // alias: hidden bf16
  ushort* yb   = (ushort*)(ws + 201326592);   // 32 MiB
  ushort* wkvt = (ushort*)(ws + 234881024);   // 4 MiB
  ushort* w1t  = (ushort*)(ws + 239075328);   // 16 MiB (GLU 64-group interleave)
  ushort* w2t  = (ushort*)(ws + 255852544);   // 8 MiB
  ushort* qb   = (ushort*)(ws + 264241152);   // 128 KiB

  conv_x_kernel<<<32768, 256, 0, stream>>>(x, xb);
  conv_q_kernel<<<64, 256, 0, stream>>>(q, qb);
  transpose_w_kernel<<<dim3(64, 32),  256, 0, stream>>>(Wkv, wkvt, 1024, 2048, 0);
  transpose_w_kernel<<<dim3(256, 32), 256, 0, stream>>>(W1,  w1t,  1024, 8192, 1);
  transpose_w_kernel<<<dim3(32, 128), 256, 0, stream>>>(W2,  w2t,  4096, 1024, 0);

  gemm_bt<0, 1024, 2048><<<4096, 256, 0, stream>>>(xb, wkvt, nullptr, kvb, nullptr, nullptr);
  attn_kernel<<<4096, 256, 0, stream>>>(kvb, qb, mask, yf);
  ln_kernel<<<16384, 256, 0, stream>>>(yf, yb, lng, lnb);
  gemm_bt<1, 1024, 8192><<<8192, 256, 0, stream>>>(yb, w1t, nullptr, hid, b1, nullptr);
  gemm_bt<2, 4096, 1024><<<1024, 256, 0, stream>>>(hid, w2t, out, nullptr, b2, yf);
}